// Round 1
// baseline (319.887 us; speedup 1.0000x reference)
//
#include <hip/hip_runtime.h>

// LSTM: B=32768, T=50, I=2, H=32 (4H=128 gates), out = h @ W_out.T + b_out
// One wave (64 lanes) per 8 batch rows. Lane L owns W_hh rows L and 64+L in
// registers (64 VGPRs): lanes 0-31 -> (i_j, g_j), lanes 32-63 -> (f_j, o_j).
// Rows processed in pairs; one shfl_xor(32) exchange gives each lane a full
// (i,f,g,o) set for one (row, unit) -> activations done exactly once.
// log2(e) scales folded into weights so sigmoid/tanh = 1 v_exp + 1 v_rcp each.

#define T_STEPS 50
#define HID 32
#define M_ROWS 8
#define HSTR 36   // h_lds row stride (floats): 16B-aligned (144B), bank-rotated

__device__ __forceinline__ float fast_exp2(float x) {
#if __has_builtin(__builtin_amdgcn_exp2f)
    return __builtin_amdgcn_exp2f(x);
#else
    return exp2f(x);
#endif
}
__device__ __forceinline__ float fast_rcp(float x) {
#if __has_builtin(__builtin_amdgcn_rcpf)
    return __builtin_amdgcn_rcpf(x);
#else
    return 1.0f / x;
#endif
}
// 1 / (1 + exp2(z))
__device__ __forceinline__ float rcp1p(float z) {
    return fast_rcp(1.0f + fast_exp2(z));
}

__global__ __launch_bounds__(64, 4)
void lsnn_kernel(const float* __restrict__ x,
                 const float* __restrict__ W_ih,
                 const float* __restrict__ W_hh,
                 const float* __restrict__ b_ih,
                 const float* __restrict__ b_hh,
                 const float* __restrict__ W_out,
                 const float* __restrict__ b_out,
                 const float* __restrict__ h0,
                 const float* __restrict__ c0,
                 float* __restrict__ out)
{
    __shared__ float x_lds[M_ROWS * T_STEPS * 2];   // 800 floats
    __shared__ float h_lds[M_ROWS * HSTR];          // 288 floats
    __shared__ float out_lds[M_ROWS * T_STEPS];     // 400 floats

    const int lane = threadIdx.x;       // 0..63
    const int j    = lane & 31;         // hidden unit index
    const int half = lane >> 5;         // 0: (i,g) lanes, 1: (f,o) lanes
    const long b0  = (long)blockIdx.x * M_ROWS;

    // ---- stage x chunk: 800 contiguous floats, coalesced float4 ----
    {
        const float4* xsrc = (const float4*)(x + b0 * (T_STEPS * 2));
        for (int idx = lane; idx < (M_ROWS * T_STEPS * 2) / 4; idx += 64)
            ((float4*)x_lds)[idx] = xsrc[idx];
    }
    // ---- init h state from h0 ----
    for (int idx = lane; idx < M_ROWS * HID; idx += 64) {
        int r = idx >> 5, jj = idx & 31;
        h_lds[r * HSTR + jj] = h0[b0 * HID + idx];
    }

    // ---- per-lane constants (scales folded: sigmoid uses exp2(-log2e*z),
    //      tanh uses exp2(2*log2e*z)) ----
    const float SGN = -1.442695040888963f;   // sigmoid gates (i,f,o)
    const float SG  =  2.885390081777927f;   // tanh gate (g) and tanh(c)
    const int   g0  = lane;                  // i_j (low) / f_j (high)
    const int   g1  = 64 + lane;             // g_j (low) / o_j (high)
    const float s0  = SGN;
    const float s1  = (half == 0) ? SG : SGN;

    float Wr0[HID], Wr1[HID];
    #pragma unroll
    for (int kq = 0; kq < HID / 4; ++kq) {
        float4 w0 = ((const float4*)(W_hh + (long)g0 * HID))[kq];
        float4 w1 = ((const float4*)(W_hh + (long)g1 * HID))[kq];
        Wr0[kq*4+0] = w0.x * s0; Wr0[kq*4+1] = w0.y * s0;
        Wr0[kq*4+2] = w0.z * s0; Wr0[kq*4+3] = w0.w * s0;
        Wr1[kq*4+0] = w1.x * s1; Wr1[kq*4+1] = w1.y * s1;
        Wr1[kq*4+2] = w1.z * s1; Wr1[kq*4+3] = w1.w * s1;
    }
    const float wih0_0 = W_ih[g0*2+0] * s0, wih0_1 = W_ih[g0*2+1] * s0;
    const float wih1_0 = W_ih[g1*2+0] * s1, wih1_1 = W_ih[g1*2+1] * s1;
    const float bias0  = (b_ih[g0] + b_hh[g0]) * s0;
    const float bias1  = (b_ih[g1] + b_hh[g1]) * s1;
    const float wout   = W_out[j];
    const float bout   = b_out[0];

    // c state: lane handles row 2p+half of pair p
    float cst[M_ROWS / 2];
    #pragma unroll
    for (int p = 0; p < M_ROWS / 2; ++p)
        cst[p] = c0[(b0 + 2*p + half) * HID + j];

    __syncthreads();  // single-wave block: cheap

    #pragma unroll 1
    for (int t = 0; t < T_STEPS; ++t) {
        #pragma unroll
        for (int p = 0; p < M_ROWS / 2; ++p) {
            const int m0 = 2 * p, m1 = 2 * p + 1;
            // input projection (prescaled)
            float2 xa = *(const float2*)&x_lds[m0 * (T_STEPS*2) + t*2];
            float2 xb = *(const float2*)&x_lds[m1 * (T_STEPS*2) + t*2];
            float a00 = fmaf(xa.y, wih0_1, fmaf(xa.x, wih0_0, bias0)); // g0,m0
            float a01 = fmaf(xb.y, wih0_1, fmaf(xb.x, wih0_0, bias0)); // g0,m1
            float a10 = fmaf(xa.y, wih1_1, fmaf(xa.x, wih1_0, bias1)); // g1,m0
            float a11 = fmaf(xb.y, wih1_1, fmaf(xb.x, wih1_0, bias1)); // g1,m1
            // recurrent dot: h broadcast from LDS (same-addr b128 reads)
            #pragma unroll
            for (int kq = 0; kq < HID / 4; ++kq) {
                float4 hA = *(const float4*)&h_lds[m0 * HSTR + kq*4];
                float4 hB = *(const float4*)&h_lds[m1 * HSTR + kq*4];
                a00 = fmaf(hA.x, Wr0[kq*4+0], a00);
                a00 = fmaf(hA.y, Wr0[kq*4+1], a00);
                a00 = fmaf(hA.z, Wr0[kq*4+2], a00);
                a00 = fmaf(hA.w, Wr0[kq*4+3], a00);
                a10 = fmaf(hA.x, Wr1[kq*4+0], a10);
                a10 = fmaf(hA.y, Wr1[kq*4+1], a10);
                a10 = fmaf(hA.z, Wr1[kq*4+2], a10);
                a10 = fmaf(hA.w, Wr1[kq*4+3], a10);
                a01 = fmaf(hB.x, Wr0[kq*4+0], a01);
                a01 = fmaf(hB.y, Wr0[kq*4+1], a01);
                a01 = fmaf(hB.z, Wr0[kq*4+2], a01);
                a01 = fmaf(hB.w, Wr0[kq*4+3], a01);
                a11 = fmaf(hB.x, Wr1[kq*4+0], a11);
                a11 = fmaf(hB.y, Wr1[kq*4+1], a11);
                a11 = fmaf(hB.z, Wr1[kq*4+2], a11);
                a11 = fmaf(hB.w, Wr1[kq*4+3], a11);
            }
            // half-wave exchange: each lane gets full (i,f,g,o) for one row
            float tmp0 = (half == 0) ? a01 : a00;
            float tmp1 = (half == 0) ? a11 : a10;
            float rx0 = __shfl_xor(tmp0, 32);
            float rx1 = __shfl_xor(tmp1, 32);
            float zi = (half == 0) ? a00 : rx0;
            float zf = (half == 0) ? rx0 : a01;
            float zg = (half == 0) ? a10 : rx1;
            float zo = (half == 0) ? rx1 : a11;
            // activations: z's already carry exp2 prescale
            float iv = rcp1p(zi);                 // sigmoid(i)
            float fv = rcp1p(zf);                 // sigmoid(f)
            float ov = rcp1p(zo);                 // sigmoid(o)
            float gv = fmaf(-2.0f, rcp1p(zg), 1.0f);   // tanh(g)
            float c  = fmaf(fv, cst[p], iv * gv);
            cst[p] = c;
            float tc = fmaf(-2.0f, rcp1p(SG * c), 1.0f); // tanh(c)
            float h  = ov * tc;
            // write h for next timestep (bank-rotated, 2-way max = free)
            const int row = m0 + half;
            h_lds[row * HSTR + j] = h;
            // fused output head: 32-lane butterfly within each half
            float po = h * wout;
            po += __shfl_xor(po, 1);
            po += __shfl_xor(po, 2);
            po += __shfl_xor(po, 4);
            po += __shfl_xor(po, 8);
            po += __shfl_xor(po, 16);
            if (j == 0) out_lds[row * T_STEPS + t] = po + bout;
        }
    }

    __syncthreads();
    // coalesced flush: this wave's 400 outputs are contiguous in global
    float* odst = out + b0 * T_STEPS;
    for (int idx = lane; idx < M_ROWS * T_STEPS; idx += 64)
        odst[idx] = out_lds[idx];
}

extern "C" void kernel_launch(void* const* d_in, const int* in_sizes, int n_in,
                              void* d_out, int out_size, void* d_ws, size_t ws_size,
                              hipStream_t stream) {
    const float* x     = (const float*)d_in[0];
    const float* W_ih  = (const float*)d_in[1];
    const float* W_hh  = (const float*)d_in[2];
    const float* b_ih  = (const float*)d_in[3];
    const float* b_hh  = (const float*)d_in[4];
    const float* W_out = (const float*)d_in[5];
    const float* b_out = (const float*)d_in[6];
    const float* h0    = (const float*)d_in[7];
    const float* c0    = (const float*)d_in[8];
    float* out = (float*)d_out;

    const int B = 32768;
    dim3 grid(B / M_ROWS), block(64);
    lsnn_kernel<<<grid, block, 0, stream>>>(x, W_ih, W_hh, b_ih, b_hh,
                                            W_out, b_out, h0, c0, out);
}

// Round 2
// 175.558 us; speedup vs baseline: 1.8221x; 1.8221x over previous
//
#include <hip/hip_runtime.h>

// LSTM B=32768, T=50, I=2, H=32. One wave per 16 batch rows (2048 blocks).
// Recurrent GEMM via mfma_f32_16x16x32_bf16, split precision:
//   gates = (hh+hl)x(Wh+Wl)^T ~= hh*Wh + hl*Wh + hh*Wl   (err ~2^-18)
// C/D layout (m89): col=lane&15, row=quad*4+reg  -> tile n holds gate n>>1,
// unit (n&1)*16+col. Lane owns full (i,f,g,o) per (row,unit): in-register
// activations, c-state in registers. h round-trips LDS as packed (hl|hh) u32.
// Gate scales (-log2e / +2log2e) folded into W/bias so each sigmoid/tanh
// fused pair costs 2 exp2 + 1 rcp.

#define TS 50
#define HSTR 36  // u32 stride of h_pk rows: 144B -> 16B aligned, <=2-way banks

typedef short short8 __attribute__((ext_vector_type(8)));
typedef float f32x4 __attribute__((ext_vector_type(4)));

__device__ __forceinline__ float fast_exp2(float x) {
#if __has_builtin(__builtin_amdgcn_exp2f)
    return __builtin_amdgcn_exp2f(x);
#else
    return exp2f(x);
#endif
}
__device__ __forceinline__ float fast_rcp(float x) {
#if __has_builtin(__builtin_amdgcn_rcpf)
    return __builtin_amdgcn_rcpf(x);
#else
    return 1.0f / x;
#endif
}

__device__ __forceinline__ unsigned bf16_rne(float v) {
    unsigned u = __float_as_uint(v);
    return (u + 0x7FFFu + ((u >> 16) & 1u)) >> 16;
}
// v = hi + lo, both bf16; hi = trunc-to-bf16 (exact residual), lo = RNE(res).
// returns (lo<<16)|hi
__device__ __forceinline__ unsigned split_pack(float v) {
    unsigned u  = __float_as_uint(v);
    unsigned hi = u >> 16;
    float    hf = __uint_as_float(hi << 16);
    unsigned lo = bf16_rne(v - hf);
    return (lo << 16) | hi;
}

__global__ __launch_bounds__(64, 2)
void lsnn_kernel(const float* __restrict__ x,
                 const float* __restrict__ W_ih,
                 const float* __restrict__ W_hh,
                 const float* __restrict__ b_ih,
                 const float* __restrict__ b_hh,
                 const float* __restrict__ W_out,
                 const float* __restrict__ b_out,
                 const float* __restrict__ h0,
                 const float* __restrict__ c0,
                 float* __restrict__ out)
{
    __shared__ __align__(16) float    x_lds[16 * 100];   // 6400 B, global layout
    __shared__ __align__(16) unsigned hpk[16 * HSTR];    // 2304 B, (hl|hh) packed
    __shared__ __align__(16) float    out_lds[16 * TS];  // 3200 B

    const int lane = threadIdx.x;
    const int u0   = lane & 15;   // C col / A row / B col
    const int q    = lane >> 4;   // quad
    const long b0  = (long)blockIdx.x * 16;

    // ---- stage x: 1600 contiguous floats, coalesced ----
    {
        const float4* xs = (const float4*)(x + b0 * 100);
        float4* xd = (float4*)x_lds;
        for (int i = lane; i < 400; i += 64) xd[i] = xs[i];
    }
    // ---- init packed h from h0 ----
    for (int i = lane; i < 512; i += 64) {
        int r = i >> 5, u = i & 31;
        hpk[r * HSTR + u] = split_pack(h0[b0 * 32 + i]);
    }

    const float L2E = 1.4426950408889634f;
    const float SG  = 2.0f * L2E;   // tanh(c) exp scale

    // ---- per-lane constants ----
    short8 Bh[8], Bl[8];
    float bias[8], wx0[8], wx1[8];
    #pragma unroll
    for (int n = 0; n < 8; ++n) {
        const int   gate = n >> 1;
        const float s    = (gate == 2) ? (2.0f * L2E) : -L2E;
        const int   g    = n * 16 + u0;              // gate row index
        const float* wr  = W_hh + g * 32 + q * 8;    // 8 consecutive k
        union { unsigned u[4]; short8 s8; } uh, ul;
        #pragma unroll
        for (int p = 0; p < 4; ++p) {
            unsigned p0 = split_pack(wr[2*p]   * s);
            unsigned p1 = split_pack(wr[2*p+1] * s);
            uh.u[p] = (p0 & 0xffffu) | (p1 << 16);
            ul.u[p] = (p0 >> 16)     | (p1 & 0xffff0000u);
        }
        Bh[n] = uh.s8; Bl[n] = ul.s8;
        bias[n] = (b_ih[g] + b_hh[g]) * s;
        wx0[n]  = W_ih[g * 2 + 0] * s;
        wx1[n]  = W_ih[g * 2 + 1] * s;
    }
    float wo[8];
    {
        const float* wp = W_out + q * 8;
        #pragma unroll
        for (int j = 0; j < 8; ++j) wo[j] = wp[j];
    }
    const float bout = b_out[0];

    // c-state: set (hu,r) -> row q*4+r, unit hu*16+u0
    float cst[8];
    #pragma unroll
    for (int hu = 0; hu < 2; ++hu)
        #pragma unroll
        for (int r = 0; r < 4; ++r)
            cst[hu * 4 + r] = c0[(b0 + q * 4 + r) * 32 + hu * 16 + u0];

    __syncthreads();

    const int abase = u0 * HSTR + q * 8;   // A-frag read base (u32 idx)

    #pragma unroll 1
    for (int t = 0; t < TS; ++t) {
        // ---- read h_{t-1} A-fragment: row u0, units q*8..q*8+7 ----
        uint4 hq0 = *(const uint4*)&hpk[abase];
        uint4 hq1 = *(const uint4*)&hpk[abase + 4];
        union { unsigned u[4]; short8 s8; } Ahh, Ahl;
        Ahh.u[0] = (hq0.x & 0xffffu) | (hq0.y << 16);
        Ahh.u[1] = (hq0.z & 0xffffu) | (hq0.w << 16);
        Ahh.u[2] = (hq1.x & 0xffffu) | (hq1.y << 16);
        Ahh.u[3] = (hq1.z & 0xffffu) | (hq1.w << 16);
        Ahl.u[0] = (hq0.x >> 16) | (hq0.y & 0xffff0000u);
        Ahl.u[1] = (hq0.z >> 16) | (hq0.w & 0xffff0000u);
        Ahl.u[2] = (hq1.x >> 16) | (hq1.y & 0xffff0000u);
        Ahl.u[3] = (hq1.z >> 16) | (hq1.w & 0xffff0000u);

        // ---- xg (exact fp32) as MFMA C-operand ----
        float xr0[4], xr1[4];
        #pragma unroll
        for (int r = 0; r < 4; ++r) {
            float2 xv = *(const float2*)&x_lds[(q * 4 + r) * 100 + 2 * t];
            xr0[r] = xv.x; xr1[r] = xv.y;
        }
        f32x4 acc[8];
        #pragma unroll
        for (int n = 0; n < 8; ++n) {
            f32x4 ci;
            #pragma unroll
            for (int r = 0; r < 4; ++r)
                ci[r] = fmaf(wx1[n], xr1[r], fmaf(wx0[n], xr0[r], bias[n]));
            acc[n] = __builtin_amdgcn_mfma_f32_16x16x32_bf16(Ahh.s8, Bh[n], ci,     0, 0, 0);
            acc[n] = __builtin_amdgcn_mfma_f32_16x16x32_bf16(Ahl.s8, Bh[n], acc[n], 0, 0, 0);
            acc[n] = __builtin_amdgcn_mfma_f32_16x16x32_bf16(Ahh.s8, Bl[n], acc[n], 0, 0, 0);
        }

        // ---- output head for h_{t-1} (independent of MFMAs) ----
        {
            float po = 0.0f;
            unsigned pk0[4] = {hq0.x, hq0.y, hq0.z, hq0.w};
            unsigned pk1[4] = {hq1.x, hq1.y, hq1.z, hq1.w};
            #pragma unroll
            for (int j = 0; j < 4; ++j) {
                float hh = __uint_as_float(pk0[j] << 16);
                float hl = __uint_as_float(pk0[j] & 0xffff0000u);
                po = fmaf(hh + hl, wo[j], po);
            }
            #pragma unroll
            for (int j = 0; j < 4; ++j) {
                float hh = __uint_as_float(pk1[j] << 16);
                float hl = __uint_as_float(pk1[j] & 0xffff0000u);
                po = fmaf(hh + hl, wo[4 + j], po);
            }
            po += __shfl_xor(po, 16);
            po += __shfl_xor(po, 32);
            if (t > 0 && q == 0) out_lds[u0 * TS + (t - 1)] = po + bout;
        }

        // ---- activations: 8 (row,unit) sets, all in-register ----
        #pragma unroll
        for (int hu = 0; hu < 2; ++hu) {
            #pragma unroll
            for (int r = 0; r < 4; ++r) {
                float zi = acc[0 + hu][r];   // i (scaled -log2e)
                float zf = acc[2 + hu][r];   // f (scaled -log2e)
                float zg = acc[4 + hu][r];   // g (scaled +2log2e)
                float zo = acc[6 + hu][r];   // o (scaled -log2e)
                float Av = fast_exp2(zi);
                float Bv = fast_exp2(fminf(zg, 126.0f));
                float Ev = fast_exp2(zf);
                float R1 = fast_rcp((1.0f + Av) * (1.0f + Bv));
                float ig = (Bv - 1.0f) * R1;             // sigmoid(i)*tanh(g)
                float fv = fast_rcp(1.0f + Ev);          // sigmoid(f)
                float c  = fmaf(fv, cst[hu * 4 + r], ig);
                cst[hu * 4 + r] = c;
                float Cv = fast_exp2(zo);
                float Dv = fast_exp2(fminf(SG * c, 126.0f));
                float R2 = fast_rcp((1.0f + Cv) * (1.0f + Dv));
                float h  = (Dv - 1.0f) * R2;             // sigmoid(o)*tanh(c)
                hpk[(q * 4 + r) * HSTR + hu * 16 + u0] = split_pack(h);
            }
        }
    }

    // ---- final output head for h_49 ----
    {
        uint4 hq0 = *(const uint4*)&hpk[abase];
        uint4 hq1 = *(const uint4*)&hpk[abase + 4];
        float po = 0.0f;
        unsigned pk0[4] = {hq0.x, hq0.y, hq0.z, hq0.w};
        unsigned pk1[4] = {hq1.x, hq1.y, hq1.z, hq1.w};
        #pragma unroll
        for (int j = 0; j < 4; ++j) {
            float hh = __uint_as_float(pk0[j] << 16);
            float hl = __uint_as_float(pk0[j] & 0xffff0000u);
            po = fmaf(hh + hl, wo[j], po);
        }
        #pragma unroll
        for (int j = 0; j < 4; ++j) {
            float hh = __uint_as_float(pk1[j] << 16);
            float hl = __uint_as_float(pk1[j] & 0xffff0000u);
            po = fmaf(hh + hl, wo[4 + j], po);
        }
        po += __shfl_xor(po, 16);
        po += __shfl_xor(po, 32);
        if (q == 0) out_lds[u0 * TS + 49] = po + bout;
    }

    __syncthreads();
    // ---- coalesced flush: 800 contiguous floats ----
    {
        float4* od = (float4*)(out + b0 * 50);
        const float4* os = (const float4*)out_lds;
        for (int i = lane; i < 200; i += 64) od[i] = os[i];
    }
}

extern "C" void kernel_launch(void* const* d_in, const int* in_sizes, int n_in,
                              void* d_out, int out_size, void* d_ws, size_t ws_size,
                              hipStream_t stream) {
    const float* x     = (const float*)d_in[0];
    const float* W_ih  = (const float*)d_in[1];
    const float* W_hh  = (const float*)d_in[2];
    const float* b_ih  = (const float*)d_in[3];
    const float* b_hh  = (const float*)d_in[4];
    const float* W_out = (const float*)d_in[5];
    const float* b_out = (const float*)d_in[6];
    const float* h0    = (const float*)d_in[7];
    const float* c0    = (const float*)d_in[8];
    float* out = (float*)d_out;

    dim3 grid(32768 / 16), block(64);
    lsnn_kernel<<<grid, block, 0, stream>>>(x, W_ih, W_hh, b_ih, b_hh,
                                            W_out, b_out, h0, c0, out);
}